// Round 2
// 502.579 us; speedup vs baseline: 1.0045x; 1.0045x over previous
//
#include <hip/hip_runtime.h>

// SparseEmbedding forward: out[(b,h), :] = weight[idx[(b,h)], :]
// NE = 1,000,000 rows, C = 64 floats/row (256 B), NROWS_OUT = 4096*50 = 204,800.
//
// Strategy: 16 threads per output row, each thread copies one float4 (16 B).
// One wave64 moves 4 rows = 1 KiB. Output writes fully coalesced; each
// gathered row is a 256 B contiguous segment (DRAM-burst friendly).
//
// R2: non-temporal output stores via native clang vector type (the HIP
// float4 class type is rejected by __builtin_nontemporal_store). The output
// (52 MB/iter) is pure streaming write-once data; letting it write-allocate
// through L2 (32 MB) and Infinity Cache (256 MB) evicts the weight table,
// which is exactly L3-sized (1M rows x 256 B = 256 MB). NT stores
// (global_store_dwordx4 nt) bypass the caches, preserving weight residency
// for the random gather and cutting HBM re-fetch on the read side.

typedef float v4f __attribute__((ext_vector_type(4)));

__global__ __launch_bounds__(256) void SparseEmbedding_69011534512743_kernel(
    const int* __restrict__ indices,   // NROWS entries
    const v4f* __restrict__ weight,    // NE * 16 float4 per row
    v4f* __restrict__ out,             // NROWS * 16 float4 per row
    int nrows)
{
    const int tid   = blockIdx.x * blockDim.x + threadIdx.x;
    const int row   = tid >> 4;       // which output row
    const int chunk = tid & 15;       // which float4 within the 256 B row
    if (row < nrows) {
        const int r = indices[row];
        const v4f v = weight[(size_t)r * 16 + chunk];
        __builtin_nontemporal_store(v, &out[(size_t)row * 16 + chunk]);
    }
}

extern "C" void kernel_launch(void* const* d_in, const int* in_sizes, int n_in,
                              void* d_out, int out_size, void* d_ws, size_t ws_size,
                              hipStream_t stream) {
    const int* indices = (const int*)d_in[0];   // (B*H,) int
    const v4f* weight  = (const v4f*)d_in[1];   // (NE, C) float32, C=64 -> 16 float4
    v4f*       out     = (v4f*)d_out;           // (B*H, C) float32

    const int nrows = in_sizes[0];              // 204,800
    const int total_threads = nrows * 16;
    const int block = 256;
    const int grid  = (total_threads + block - 1) / block;

    SparseEmbedding_69011534512743_kernel<<<grid, block, 0, stream>>>(
        indices, weight, out, nrows);
}